// Round 8
// baseline (154.923 us; speedup 1.0000x reference)
//
#include <hip/hip_runtime.h>
#include <hip/hip_bf16.h>

#define DM 1024
#define DH 64
#define TT 2048

typedef __attribute__((ext_vector_type(8))) short bf16x8;
typedef __attribute__((ext_vector_type(4))) short s16x4;
typedef __attribute__((ext_vector_type(4))) float f32x4;

static __device__ __forceinline__ short f2bf(float f) {
  union { __hip_bfloat16 h; short s; } u;
  u.h = __float2bfloat16(f);
  return u.s;
}

// ---------------- kernel 1: W -> W^T bf16, layout [3][64 n][1024 k] ----------------
__global__ __launch_bounds__(256) void convw_kernel(const float* __restrict__ Wq,
                                                    const float* __restrict__ Wk,
                                                    const float* __restrict__ Wv,
                                                    short* __restrict__ Wt) {
  int idx = blockIdx.x * 256 + threadIdx.x;
  if (idx >= 3 * 64 * 1024) return;
  int wsel = idx >> 16;
  int rem  = idx & 65535;
  int n = rem >> 10;
  int k = rem & 1023;
  const float* W = (wsel == 0) ? Wq : (wsel == 1) ? Wk : Wv;
  Wt[idx] = f2bf(W[k * DH + n]);
}

// ---------------- kernel 2: projection as tiled GEMM (unchanged structure) --------
// Q outputs pre-scaled by 1/sqrt(DM) so flash needs no per-score scale.
__global__ __launch_bounds__(512, 4) void proj_kernel(const float* __restrict__ x,
                                                      const short* __restrict__ Wt,
                                                      short* __restrict__ Qb,
                                                      short* __restrict__ Kb,
                                                      short* __restrict__ Vt) {
  __shared__ short As[64 * 64];    // [row 64][k 64] bf16, swizzled, 8 KB
  __shared__ short Bs[192 * 64];   // [n 192][k 64] bf16, swizzled, 24 KB
  char* Ab = (char*)As;
  char* Bb = (char*)Bs;
  int tid  = threadIdx.x;
  int lane = tid & 63;
  int wid  = tid >> 6;
  int l15 = lane & 15, lq = lane >> 4;
  int wr = wid >> 1, wc = wid & 1;          // 4M x 2N wave grid
  int row0 = blockIdx.x * 64;

  int arow = tid >> 3, acg = tid & 7;
  const float* axp = x + (size_t)(row0 + arow) * DM + acg * 8;
  int abyte = arow * 128 + ((acg * 16) ^ ((arow & 7) << 4));
  int brow = tid >> 1, bh = tid & 1;
  const short* bwp = Wt + (size_t)brow * DM + bh * 32;
  int bswz = (brow & 7) << 4;
  int bbyte[4];
  #pragma unroll
  for (int i = 0; i < 4; ++i) bbyte[i] = brow * 128 + ((bh * 64 + i * 16) ^ bswz);

  float4 pa0 = ((const float4*)axp)[0];
  float4 pa1 = ((const float4*)axp)[1];
  bf16x8 pb[4];
  if (tid < 384) {
    #pragma unroll
    for (int i = 0; i < 4; ++i) pb[i] = ((const bf16x8*)bwp)[i];
  }

  f32x4 acc[6];
  #pragma unroll
  for (int n = 0; n < 6; ++n) acc[n] = (f32x4){0.f, 0.f, 0.f, 0.f};

  for (int s = 0; s < 16; ++s) {
    bf16x8 aw;
    aw[0] = f2bf(pa0.x); aw[1] = f2bf(pa0.y); aw[2] = f2bf(pa0.z); aw[3] = f2bf(pa0.w);
    aw[4] = f2bf(pa1.x); aw[5] = f2bf(pa1.y); aw[6] = f2bf(pa1.z); aw[7] = f2bf(pa1.w);
    *(bf16x8*)(Ab + abyte) = aw;
    if (tid < 384) {
      #pragma unroll
      for (int i = 0; i < 4; ++i) *(bf16x8*)(Bb + bbyte[i]) = pb[i];
    }
    __syncthreads();
    if (s < 15) {
      const float* nax = axp + (s + 1) * 64;
      pa0 = ((const float4*)nax)[0];
      pa1 = ((const float4*)nax)[1];
      if (tid < 384) {
        const short* nbw = bwp + (s + 1) * 64;
        #pragma unroll
        for (int i = 0; i < 4; ++i) pb[i] = ((const bf16x8*)nbw)[i];
      }
    }
    #pragma unroll
    for (int kk = 0; kk < 2; ++kk) {
      int koff = (kk * 64 + lq * 16) ^ ((l15 & 7) << 4);
      bf16x8 af = *(const bf16x8*)(Ab + (wr * 16 + l15) * 128 + koff);
      bf16x8 bf[6];
      #pragma unroll
      for (int nc = 0; nc < 6; ++nc)
        bf[nc] = *(const bf16x8*)(Bb + (wc * 96 + nc * 16 + l15) * 128 + koff);
      #pragma unroll
      for (int nc = 0; nc < 6; ++nc)
        acc[nc] = __builtin_amdgcn_mfma_f32_16x16x32_bf16(af, bf[nc], acc[nc], 0, 0, 0);
    }
    __syncthreads();
  }

  int growb = row0 + wr * 16 + lq * 4;
  #pragma unroll
  for (int nc = 0; nc < 6; ++nc) {
    int gcolb = wc * 96 + nc * 16;
    int mat = gcolb >> 6;
    int mc  = (gcolb & 63) + l15;
    if (mat == 0) {
      #pragma unroll
      for (int r = 0; r < 4; ++r)
        Qb[(size_t)(growb + r) * DH + mc] = f2bf(acc[nc][r] * 0.03125f);  // pre-scale Q
    } else if (mat == 1) {
      #pragma unroll
      for (int r = 0; r < 4; ++r)
        Kb[(size_t)(growb + r) * DH + mc] = f2bf(acc[nc][r]);
    } else {
      int b = growb >> 11;
      int tl = growb & 2047;
      s16x4 pk;
      #pragma unroll
      for (int r = 0; r < 4; ++r) pk[r] = f2bf(acc[nc][r]);
      *(s16x4*)(Vt + ((size_t)(b * DH + mc)) * TT + tl) = pk;
    }
  }
}

// ---------------- kernel 3: causal flash, 128-key pair iterations ----------------
// 4 waves/block on one 16-row Q tile; wave w handles key-pair-tiles p = w, w+4, ...
// (128 keys each: 8x16-key S-tiles jointly -> one reduce/rescale per 128 keys).
// Q pre-scaled in proj. 1024 blocks x 256 thr.
__global__ __launch_bounds__(256, 4) void flash_kernel(const short* __restrict__ Qb,
                                                       const short* __restrict__ Kb,
                                                       const short* __restrict__ Vt,
                                                       float* __restrict__ out) {
  __shared__ union ShBuf {
    short Pl[4][16][136];   // [wave][q 16][key 128 pad 136]; rows 272B, 16B-aligned
    float Om[4][16][64];    // per-wave partial O (valid after post-loop barrier)
  } sh;
  __shared__ float Mm[4][16];
  __shared__ float Lm[4][16];
  __shared__ float Sc[4][16];
  __shared__ float Linv[16];
  int w    = threadIdx.x >> 6;
  int lane = threadIdx.x & 63;
  int l15 = lane & 15, lq = lane >> 4;
  int qt = 127 - (blockIdx.x >> 3);   // descending work order for load balance
  int b  = blockIdx.x & 7;
  int row0 = qt * 16;

  const short* qp = Qb + ((size_t)(b * TT + row0 + l15)) * DH + 8 * lq;
  bf16x8 qf0 = *reinterpret_cast<const bf16x8*>(qp);
  bf16x8 qf1 = *reinterpret_cast<const bf16x8*>(qp + 32);

  float mrow[4] = {-1e30f, -1e30f, -1e30f, -1e30f};
  float lrow[4] = {0.f, 0.f, 0.f, 0.f};
  f32x4 o[4];
  #pragma unroll
  for (int nt = 0; nt < 4; ++nt) o[nt] = (f32x4){0.f, 0.f, 0.f, 0.f};

  int nkt = (qt >> 2) + 1;            // causal 64-key tiles
  int npair = (nkt + 1) >> 1;         // 128-key pair tiles
  for (int p = w; p < npair; p += 4) {
    int k0 = p * 128;
    // ---- S = Q K^T for 8 sub-tiles (16 independent MFMAs) ----
    f32x4 s[8];
    #pragma unroll
    for (int nt = 0; nt < 8; ++nt) {
      const short* kp = Kb + ((size_t)(b * TT + k0 + nt * 16 + l15)) * DH + 8 * lq;
      bf16x8 b0 = *reinterpret_cast<const bf16x8*>(kp);
      bf16x8 b1 = *reinterpret_cast<const bf16x8*>(kp + 32);
      f32x4 t = (f32x4){0.f, 0.f, 0.f, 0.f};
      t = __builtin_amdgcn_mfma_f32_16x16x32_bf16(qf0, b0, t, 0, 0, 0);
      t = __builtin_amdgcn_mfma_f32_16x16x32_bf16(qf1, b1, t, 0, 0, 0);
      s[nt] = t;
    }
    // ---- causal mask + row max (S already scaled via Q) ----
    // D layout: col(=key within tile)=l15, row(=q)=lq*4+r
    float rmax[4] = {-1e30f, -1e30f, -1e30f, -1e30f};
    #pragma unroll
    for (int nt = 0; nt < 8; ++nt) {
      int key = k0 + nt * 16 + l15;
      #pragma unroll
      for (int r = 0; r < 4; ++r) {
        int qr = row0 + lq * 4 + r;
        float v = s[nt][r];
        v = (key <= qr) ? v : -1e30f;
        s[nt][r] = v;
        rmax[r] = fmaxf(rmax[r], v);
      }
    }
    #pragma unroll
    for (int r = 0; r < 4; ++r)
      #pragma unroll
      for (int d = 1; d < 16; d <<= 1)
        rmax[r] = fmaxf(rmax[r], __shfl_xor(rmax[r], d));
    // ---- online softmax update (one pass per 128 keys) ----
    float alpha[4], rs[4];
    #pragma unroll
    for (int r = 0; r < 4; ++r) {
      float mn = fmaxf(mrow[r], rmax[r]);
      alpha[r] = __expf(mrow[r] - mn);
      mrow[r] = mn;
      rs[r] = 0.f;
    }
    #pragma unroll
    for (int nt = 0; nt < 8; ++nt)
      #pragma unroll
      for (int r = 0; r < 4; ++r) {
        float pv = __expf(s[nt][r] - mrow[r]);
        s[nt][r] = pv;
        rs[r] += pv;
      }
    #pragma unroll
    for (int r = 0; r < 4; ++r) {
      #pragma unroll
      for (int d = 1; d < 16; d <<= 1)
        rs[r] += __shfl_xor(rs[r], d);
      lrow[r] = lrow[r] * alpha[r] + rs[r];
    }
    #pragma unroll
    for (int nt = 0; nt < 4; ++nt) {
      o[nt][0] *= alpha[0]; o[nt][1] *= alpha[1];
      o[nt][2] *= alpha[2]; o[nt][3] *= alpha[3];
    }
    // ---- P (D-layout) -> LDS transpose -> A-operand layout (wave-private) ----
    #pragma unroll
    for (int nt = 0; nt < 8; ++nt)
      #pragma unroll
      for (int r = 0; r < 4; ++r)
        sh.Pl[w][lq * 4 + r][nt * 16 + l15] = f2bf(s[nt][r]);
    // same-wave DS ops in-order; buffer wave-private -> no barrier
    bf16x8 pa[4];
    #pragma unroll
    for (int h = 0; h < 4; ++h)
      pa[h] = *reinterpret_cast<const bf16x8*>(&sh.Pl[w][l15][h * 32 + 8 * lq]);
    // ---- O += P V over 128 keys ----
    #pragma unroll
    for (int nt = 0; nt < 4; ++nt) {
      const short* vp = Vt + ((size_t)(b * DH + nt * 16 + l15)) * TT + k0 + 8 * lq;
      #pragma unroll
      for (int h = 0; h < 4; ++h) {
        bf16x8 vf = *reinterpret_cast<const bf16x8*>(vp + 32 * h);
        o[nt] = __builtin_amdgcn_mfma_f32_16x16x32_bf16(pa[h], vf, o[nt], 0, 0, 0);
      }
    }
  }
  // ---- all waves done with Pl before Om overwrites it (union hazard) ----
  __syncthreads();
  #pragma unroll
  for (int nt = 0; nt < 4; ++nt)
    #pragma unroll
    for (int r = 0; r < 4; ++r)
      sh.Om[w][lq * 4 + r][nt * 16 + l15] = o[nt][r];
  if (l15 == 0) {
    #pragma unroll
    for (int r = 0; r < 4; ++r) {
      Mm[w][lq * 4 + r] = mrow[r];
      Lm[w][lq * 4 + r] = lrow[r];
    }
  }
  __syncthreads();
  // ---- per-row combine factors ----
  if (threadIdx.x < 16) {
    int row = threadIdx.x;
    float M = -1e30f;
    #pragma unroll
    for (int v = 0; v < 4; ++v) M = fmaxf(M, Mm[v][row]);
    float L = 0.f;
    #pragma unroll
    for (int v = 0; v < 4; ++v) {
      float sv = __expf(Mm[v][row] - M);
      Sc[v][row] = sv;
      L += Lm[v][row] * sv;
    }
    Linv[row] = 1.0f / L;
  }
  __syncthreads();
  // ---- merge: 1024 outputs over 256 threads, coalesced ----
  int e = threadIdx.x;
  #pragma unroll
  for (int i = 0; i < 4; ++i, e += 256) {
    int row = e >> 6, col = e & 63;
    float val = 0.f;
    #pragma unroll
    for (int v = 0; v < 4; ++v) val += sh.Om[v][row][col] * Sc[v][row];
    out[((size_t)(b * TT + row0 + row)) * DH + col] = val * Linv[row];
  }
}

extern "C" void kernel_launch(void* const* d_in, const int* in_sizes, int n_in,
                              void* d_out, int out_size, void* d_ws, size_t ws_size,
                              hipStream_t stream) {
  const float* x  = (const float*)d_in[0];
  const float* Wq = (const float*)d_in[1];
  const float* Wk = (const float*)d_in[2];
  const float* Wv = (const float*)d_in[3];
  float* out = (float*)d_out;
  char* ws = (char*)d_ws;
  // workspace layout (bf16): Qb 2MB | Kb 2MB | Vt 2MB | Wt 0.4MB
  short* Qb = (short*)(ws);
  short* Kb = (short*)(ws + (2ull << 20));
  short* Vt = (short*)(ws + (4ull << 20));
  short* Wt = (short*)(ws + (6ull << 20));

  convw_kernel<<<dim3(768), dim3(256), 0, stream>>>(Wq, Wk, Wv, Wt);
  proj_kernel<<<dim3(256), dim3(512), 0, stream>>>(x, Wt, Qb, Kb, Vt);
  flash_kernel<<<dim3(1024), dim3(256), 0, stream>>>(Qb, Kb, Vt, out);
}